// Round 2
// baseline (572.608 us; speedup 1.0000x reference)
//
#include <hip/hip_runtime.h>

// CombineUV: out[b,s] = <input[b,:]*sig(alpha), W[l,:]> + <input[b,:]*sig(beta), V[l,:]> + bias[l]
// with l = shortlist[b,s]. Never materializes the [L,D] gated matrix.
// L=131072, D=512, B=512, S=512. Memory-bound on the ~1 GiB row gather.
// NOTE: harness delivers ALL integer inputs as int32 (shortlist int64 in the
// reference arrives as const int*). Reading it as long long caused the R1 fault.

#define D_DIM 512
#define S_DIM 512

__global__ void combine_uv_kernel(
    const float* __restrict__ input,     // [B, D]
    const float* __restrict__ labels,    // [L, D]  'v'
    const float* __restrict__ weight,    // [L, D]  'u'
    const float* __restrict__ alpha,     // [1, D]
    const float* __restrict__ beta,      // [1, D]
    const float* __restrict__ bias,      // [L]
    const int* __restrict__ shortlist,   // [B, S] (int32 on device)
    float* __restrict__ out)             // [B, S]
{
    __shared__ float ga[D_DIM];   // input[b,:] * sigmoid(alpha)
    __shared__ float gb[D_DIM];   // input[b,:] * sigmoid(beta)
    __shared__ int sl[64];        // this block's shortlist slice

    const int b   = blockIdx.x;
    const int s0  = blockIdx.y * 64;
    const int tid = threadIdx.x;

    // Stage gated input row into LDS (sigmoid cost: 512 exp per block, trivial).
    for (int d = tid; d < D_DIM; d += 256) {
        float x  = input[b * D_DIM + d];
        float sa = 1.0f / (1.0f + __expf(-alpha[d]));
        float sb = 1.0f / (1.0f + __expf(-beta[d]));
        ga[d] = x * sa;
        gb[d] = x * sb;
    }
    if (tid < 64) sl[tid] = shortlist[b * S_DIM + s0 + tid];
    __syncthreads();

    const int wave = tid >> 6;   // 0..3
    const int lane = tid & 63;

    // Lane fragment of ga/gb: elements [lane*4, lane*4+4) and [256+lane*4, ...)
    float a0[4], a1[4], b0v[4], b1v[4];
    #pragma unroll
    for (int k = 0; k < 4; ++k) {
        a0[k]  = ga[lane * 4 + k];
        a1[k]  = ga[256 + lane * 4 + k];
        b0v[k] = gb[lane * 4 + k];
        b1v[k] = gb[256 + lane * 4 + k];
    }

    // Each wave: 16 s values, unrolled x2 for memory-level parallelism.
    for (int j = 0; j < 16; j += 2) {
        const int si0 = wave * 16 + j;
        const int si1 = si0 + 1;
        const long long l0 = (long long)sl[si0];
        const long long l1 = (long long)sl[si1];

        const float4* w0 = (const float4*)(weight + l0 * D_DIM);
        const float4* v0 = (const float4*)(labels + l0 * D_DIM);
        const float4* w1 = (const float4*)(weight + l1 * D_DIM);
        const float4* v1 = (const float4*)(labels + l1 * D_DIM);

        // 8 coalesced 16B loads in flight (64 lanes x 16B = 1KB each)
        float4 w0a = w0[lane];      float4 w0b = w0[64 + lane];
        float4 v0a = v0[lane];      float4 v0b = v0[64 + lane];
        float4 w1a = w1[lane];      float4 w1b = w1[64 + lane];
        float4 v1a = v1[lane];      float4 v1b = v1[64 + lane];

        float acc0 = w0a.x * a0[0] + w0a.y * a0[1] + w0a.z * a0[2] + w0a.w * a0[3]
                   + w0b.x * a1[0] + w0b.y * a1[1] + w0b.z * a1[2] + w0b.w * a1[3]
                   + v0a.x * b0v[0] + v0a.y * b0v[1] + v0a.z * b0v[2] + v0a.w * b0v[3]
                   + v0b.x * b1v[0] + v0b.y * b1v[1] + v0b.z * b1v[2] + v0b.w * b1v[3];

        float acc1 = w1a.x * a0[0] + w1a.y * a0[1] + w1a.z * a0[2] + w1a.w * a0[3]
                   + w1b.x * a1[0] + w1b.y * a1[1] + w1b.z * a1[2] + w1b.w * a1[3]
                   + v1a.x * b0v[0] + v1a.y * b0v[1] + v1a.z * b0v[2] + v1a.w * b0v[3]
                   + v1b.x * b1v[0] + v1b.y * b1v[1] + v1b.z * b1v[2] + v1b.w * b1v[3];

        // 64-lane butterfly reduction on both accumulators
        #pragma unroll
        for (int off = 32; off > 0; off >>= 1) {
            acc0 += __shfl_down(acc0, off, 64);
            acc1 += __shfl_down(acc1, off, 64);
        }

        if (lane == 0) {
            out[b * S_DIM + s0 + si0] = acc0 + bias[l0];
            out[b * S_DIM + s0 + si1] = acc1 + bias[l1];
        }
    }
}

extern "C" void kernel_launch(void* const* d_in, const int* in_sizes, int n_in,
                              void* d_out, int out_size, void* d_ws, size_t ws_size,
                              hipStream_t stream) {
    const float* input     = (const float*)d_in[0];
    const float* labels    = (const float*)d_in[1];
    const float* weight    = (const float*)d_in[2];
    const float* alpha     = (const float*)d_in[3];
    const float* beta      = (const float*)d_in[4];
    const float* bias      = (const float*)d_in[5];
    const int* shortlist   = (const int*)d_in[6];
    float* out             = (float*)d_out;

    const int B = 512;
    const int S = 512;
    dim3 grid(B, S / 64);   // 4096 blocks
    dim3 block(256);
    combine_uv_kernel<<<grid, block, 0, stream>>>(
        input, labels, weight, alpha, beta, bias, shortlist, out);
}